// Round 10
// baseline (192.169 us; speedup 1.0000x reference)
//
#include <hip/hip_runtime.h>
#include <hip/hip_bf16.h>
#include <cstdint>
#include <cstddef>

typedef __bf16 bf16;
typedef __attribute__((ext_vector_type(4))) float f32x4;
typedef __attribute__((ext_vector_type(16))) float f32x16;
typedef __attribute__((ext_vector_type(8))) __bf16 bf16x8;
typedef __attribute__((ext_vector_type(4))) __bf16 bf16x4;
typedef __attribute__((ext_vector_type(4))) unsigned int u32x4;

#define D_MODEL 1024
#define NHEADS  16
#define DHEAD   64
#define SEQ     2048
#define BATCH   2
#define MROWS   (BATCH*SEQ)   /* 4096 */
#define BHTOT   (BATCH*NHEADS) /* 32 */

// 0.125 (1/sqrt(64)) * log2(e): fold into q so softmax uses exp2
#define QSCALE 0.18033688011112042f
// defer-max threshold in log2 units (HK's THR=8 nats * log2e)
#define DEFER_THR 11.5f

__device__ __forceinline__ void gload16(const bf16* g, bf16* l) {
  __builtin_amdgcn_global_load_lds(
      (const __attribute__((address_space(1))) void*)g,
      (__attribute__((address_space(3))) void*)l, 16, 0, 0);
}

__device__ __forceinline__ f32x4 mfma16(bf16x8 a, bf16x8 b, f32x4 c) {
  return __builtin_amdgcn_mfma_f32_16x16x32_bf16(a, b, c, 0, 0, 0);
}

__device__ __forceinline__ f32x16 mfma32(bf16x8 a, bf16x8 b, f32x16 c) {
  return __builtin_amdgcn_mfma_f32_32x32x16_bf16(a, b, c, 0, 0, 0);
}

// raw v_exp_f32 (skip libm range-fixup; |x| well within range here)
__device__ __forceinline__ float fexp2(float x) {
#if __has_builtin(__builtin_amdgcn_exp2f)
  return __builtin_amdgcn_exp2f(x);
#else
  float r; asm("v_exp_f32 %0, %1" : "=v"(r) : "v"(x)); return r;
#endif
}

// pack two f32 -> one u32 of 2 bf16 (lo = first arg)
__device__ __forceinline__ unsigned cvtpk(float lo, float hi) {
  unsigned r;
  asm("v_cvt_pk_bf16_f32 %0, %1, %2" : "=v"(r) : "v"(lo), "v"(hi));
  return r;
}

// ---------------- prep kernels ----------------

__global__ void cast_f32_bf16(const float* __restrict__ in, bf16* __restrict__ out, int n4) {
  int i = blockIdx.x * blockDim.x + threadIdx.x;
  if (i >= n4) return;
  float4 v = ((const float4*)in)[i];
  bf16x4 o;
  o[0] = (bf16)v.x; o[1] = (bf16)v.y; o[2] = (bf16)v.z; o[3] = (bf16)v.w;
  ((bf16x4*)out)[i] = o;
}

// in [R][C] fp32  ->  out [C][R] bf16
__global__ void tcast(const float* __restrict__ in, bf16* __restrict__ out, int R, int C) {
  __shared__ float t[32][33];
  int c0 = blockIdx.x * 32, r0 = blockIdx.y * 32;
  int tx = threadIdx.x, ty = threadIdx.y;
  #pragma unroll
  for (int i = 0; i < 4; i++)
    t[ty + i*8][tx] = in[(size_t)(r0 + ty + i*8) * C + c0 + tx];
  __syncthreads();
  #pragma unroll
  for (int i = 0; i < 4; i++)
    out[(size_t)(c0 + ty + i*8) * R + r0 + tx] = (bf16)t[tx][ty + i*8];
}

// ---------------- GEMM: C[M][N] = A[M][K](bf16) * Bt[N][K](bf16)^T ----------------
// BK=64, XOR-swizzled LDS (pre-swizzled global source + swizzled ds_read, rule 21).
// EPI 0: scatter q/k head-major (q scaled by QSCALE) and v directly TRANSPOSED
//        into vt[BH][64][SEQ]; EPI 1: fp32 out = acc + x.

template <int EPI>
__global__ __launch_bounds__(256, 3) void gemm_bt(
    const bf16* __restrict__ A, const bf16* __restrict__ Bt, int K, int N,
    bf16* __restrict__ qb, bf16* __restrict__ kb, bf16* __restrict__ vtb,
    const float* __restrict__ xres, float* __restrict__ outf) {
  __shared__ alignas(16) bf16 As[128 * 64];
  __shared__ alignas(16) bf16 Bs[128 * 64];
  const int tid = threadIdx.x;
  const int wave = tid >> 6, lane = tid & 63;
  const int wr = wave >> 1, wc = wave & 1;
  const int m0 = blockIdx.y * 128, n0 = blockIdx.x * 128;
  const int srow = lane >> 3;                    // row within 8-row chunk
  const int scol = ((lane & 7) ^ srow) * 8;      // pre-swizzled source column
  const int lr16 = lane & 15, lg = lane >> 4;
  const int rsw = (lr16 & 7) << 4;
  const int cA = (lg * 16) ^ rsw;
  const int cB = (64 + lg * 16) ^ rsw;
  const char* aP = (const char*)As + (wr*64 + lr16) * 128;
  const char* bP = (const char*)Bs + (wc*64 + lr16) * 128;

  f32x4 acc[4][4];
  #pragma unroll
  for (int m = 0; m < 4; m++)
    #pragma unroll
    for (int n = 0; n < 4; n++) acc[m][n] = (f32x4)0.0f;

  for (int k0 = 0; k0 < K; k0 += 64) {
    #pragma unroll
    for (int j = 0; j < 4; j++) {
      const int c = wave * 4 + j;                // 8-row chunk index (0..15)
      gload16(A  + (size_t)(m0 + c*8 + srow) * K + k0 + scol, &As[c * 512]);
      gload16(Bt + (size_t)(n0 + c*8 + srow) * K + k0 + scol, &Bs[c * 512]);
    }
    __syncthreads();
    bf16x8 af[4][2], bfr[4][2];
    #pragma unroll
    for (int m = 0; m < 4; m++) {
      af[m][0] = *(const bf16x8*)(aP + m*2048 + cA);
      af[m][1] = *(const bf16x8*)(aP + m*2048 + cB);
    }
    #pragma unroll
    for (int n = 0; n < 4; n++) {
      bfr[n][0] = *(const bf16x8*)(bP + n*2048 + cA);
      bfr[n][1] = *(const bf16x8*)(bP + n*2048 + cB);
    }
    #pragma unroll
    for (int m = 0; m < 4; m++)
      #pragma unroll
      for (int n = 0; n < 4; n++) {
        acc[m][n] = mfma16(af[m][0], bfr[n][0], acc[m][n]);
        acc[m][n] = mfma16(af[m][1], bfr[n][1], acc[m][n]);
      }
    __syncthreads();
  }

  #pragma unroll
  for (int n = 0; n < 4; n++) {
    const int colg = n0 + wc*64 + n*16 + lr16;
    if (EPI == 0) {
      const int which = colg >> 10;           // 0=q 1=k 2=v
      const int win = colg & 1023;
      const int h = win >> 6, d = win & 63;
      #pragma unroll
      for (int m = 0; m < 4; m++) {
        const int rowg0 = m0 + wr*64 + m*16 + lg*4;
        #pragma unroll
        for (int j = 0; j < 4; j++) {
          const int rowg = rowg0 + j;
          const int b = rowg >> 11, r = rowg & 2047;
          const int bh = (b << 4) + h;
          if (which == 2) {
            // v -> transposed layout vt[bh][d][r]
            vtb[((size_t)bh * DHEAD + d) * SEQ + r] = (bf16)acc[m][n][j];
          } else {
            bf16* dst = (which == 0) ? qb : kb;
            const float sc = (which == 0) ? QSCALE : 1.0f;
            dst[((size_t)bh * SEQ + r) * DHEAD + d] = (bf16)(acc[m][n][j] * sc);
          }
        }
      }
    } else {
      #pragma unroll
      for (int m = 0; m < 4; m++) {
        const int rowg0 = m0 + wr*64 + m*16 + lg*4;
        #pragma unroll
        for (int j = 0; j < 4; j++) {
          const size_t idx = (size_t)(rowg0 + j) * N + colg;
          outf[idx] = acc[m][n][j] + xres[idx];
        }
      }
    }
  }
}

// ---------------- flash attention: 32x32x16 MFMA, in-block KV split ----------------
// 512-thread block = 8 waves: wave w -> (q-subtile qw = w&3 [32 rows], kv-half
// kh2 = w>>2 [1024 kv]). K is LDS-staged (double-buffered, swizzled) per kv-half;
// V is read DIRECT from global (vt[bh][d][kv]: each PV A-fragment is a contiguous
// 16B lane load; V is L2-resident at 256KB/head) — removes 8 ds_reads + 2 staging
// ops per iter (R9 showed the DS pipe was the most-loaded resource). P stays
// reg-resident: cvtpk + 2x shfl_xor(32) per fragment-pair (halved vs R8: each side
// sends exactly the two words its partner needs). Partner kv-halves merge
// online-softmax partials exactly via LDS at the end.
__global__ __launch_bounds__(512, 4) void attn_kernel(
    const bf16* __restrict__ q, const bf16* __restrict__ k,
    const bf16* __restrict__ vt, bf16* __restrict__ o) {
  // staging: [kh2:16KB][buf:8KB] bf16 K tiles; merge area (35840B) aliases after loop
  __shared__ alignas(16) char smraw[36864];
  bf16* kvb = (bf16*)smraw;
  float* mg = (float*)smraw;

  const int tid = threadIdx.x;
  const int wave = tid >> 6, lane = tid & 63;
  const int qw = wave & 3, kh2 = wave >> 2;
  const int l31 = lane & 31, hi = lane >> 5;
  const int bh = blockIdx.y;
  const int b = bh >> 4, h = bh & 15;
  const int qr = blockIdx.x * 128 + qw * 32;
  const bf16* kh = k  + (size_t)bh * SEQ * DHEAD;
  const bf16* vh = vt + (size_t)bh * DHEAD * SEQ;

  // K staging: within a kv-half, wave qw covers rows [qw*16, qw*16+16) of the 64-row tile
  const int srow = lane >> 3;
  const int scol = ((lane & 7) ^ srow) * 8;
  const bf16* kg = kh + (size_t)(kh2 * 1024 + qw * 16 + srow) * DHEAD + scol;
  bf16* ldsK0 = kvb + kh2 * 8192 +        qw * 1024;
  bf16* ldsK1 = kvb + kh2 * 8192 + 4096 + qw * 1024;

  // V direct-read bases: d-row = l31 (acc0) / 32+l31 (acc1), col = kv
  const bf16* v0p = vh + (size_t)l31 * SEQ + kh2 * 1024 + hi * 8;
  const bf16* v1p = vh + (size_t)(32 + l31) * SEQ + kh2 * 1024 + hi * 8;

  // Q fragments (B operand): lane holds q-row (qr+l31), k = ks*16 + hi*8 + j
  const bf16* qrow = q + (size_t)bh * SEQ * DHEAD + (size_t)(qr + l31) * DHEAD;
  bf16x8 qf[4];
  #pragma unroll
  for (int ks = 0; ks < 4; ks++)
    qf[ks] = *(const bf16x8*)&qrow[ks * 16 + hi * 8];

  float mr = 0.0f, lsum = 0.0f;
  f32x16 acc0 = (f32x16)0.0f, acc1 = (f32x16)0.0f;  // O^T d-tiles 0..31 / 32..63

  // hoisted K read offsets: row = l31 (+32 for half 1), col slot XOR-swizzled by row&7
  const int rsw = (lane & 7) << 4;
  const int rowoff = l31 * 128;
  int cofs[4];
  #pragma unroll
  for (int ks = 0; ks < 4; ks++) cofs[ks] = (ks * 32 + hi * 16) ^ rsw;
  const char* kr0 = (const char*)(kvb + kh2 * 8192) + rowoff;
  const char* kr1 = (const char*)(kvb + kh2 * 8192 + 4096) + rowoff;

  // prologue: stage K tile 0 into buf 0
  gload16(kg, ldsK0); gload16(kg + 8 * DHEAD, ldsK0 + 512);
  kg += 64 * DHEAD;
  __syncthreads();

  const int NT = 1024 / 64;   // 16 iters per kv-half
  for (int t = 0; t < NT; ++t) {
    // stage next K tile into the other buffer (wave-uniform selects, no arrays)
    bf16* dK = (t & 1) ? ldsK0 : ldsK1;
    if (t + 1 < NT) {
      gload16(kg, dK); gload16(kg + 8 * DHEAD, dK + 512);
      kg += 64 * DHEAD;
    }
    const char* kr = (t & 1) ? kr1 : kr0;
    const int kv0 = t * 64;

    // issue all 8 V fragment loads for this tile now; consumed in PV after softmax
    bf16x8 vfa0, vfa1, vfb0, vfb1, vfc0, vfc1, vfd0, vfd1;
    vfa0 = *(const bf16x8*)(v0p + kv0);      vfa1 = *(const bf16x8*)(v1p + kv0);
    vfb0 = *(const bf16x8*)(v0p + kv0 + 16); vfb1 = *(const bf16x8*)(v1p + kv0 + 16);
    vfc0 = *(const bf16x8*)(v0p + kv0 + 32); vfc1 = *(const bf16x8*)(v1p + kv0 + 32);
    vfd0 = *(const bf16x8*)(v0p + kv0 + 48); vfd1 = *(const bf16x8*)(v1p + kv0 + 48);

    // two 32-kv halves, fully sequential (low register peak)
    #pragma unroll
    for (int th = 0; th < 2; ++th) {
      const int toff = th * 4096;   // +32 kv rows in K tile

      // ---- QK^T (swapped): one 32x32 S^T tile, C-init = -mr
      const float nmr = -mr;
      f32x16 s = (f32x16)nmr;
      __builtin_amdgcn_s_setprio(1);
      #pragma unroll
      for (int ks = 0; ks < 4; ks++) {
        bf16x8 kf = *(const bf16x8*)(kr + toff + cofs[ks]);
        s = mfma32(kf, qf[ks], s);
      }
      __builtin_amdgcn_s_setprio(0);

      // ---- defer-max: tree max over the lane's 16 scores
      const float a0 = fmaxf(fmaxf(s[0], s[1]), fmaxf(s[2], s[3]));
      const float a1 = fmaxf(fmaxf(s[4], s[5]), fmaxf(s[6], s[7]));
      const float a2 = fmaxf(fmaxf(s[8], s[9]), fmaxf(s[10], s[11]));
      const float a3 = fmaxf(fmaxf(s[12], s[13]), fmaxf(s[14], s[15]));
      const float lmax = fmaxf(fmaxf(a0, a1), fmaxf(a2, a3));

      if (!__all(lmax <= DEFER_THR)) {       // rare: rescale
        float mx = fmaxf(lmax, __shfl_xor(lmax, 32));
        mx = fmaxf(mx, 0.0f);
        const float corr = fexp2(-mx);
        lsum *= corr;
        acc0 *= corr; acc1 *= corr;
        mr += mx;
        #pragma unroll
        for (int r = 0; r < 16; r++) s[r] -= mx;
      }

      // ---- exp2 + per-lane partial sum
      #pragma unroll
      for (int r = 0; r < 16; r++) s[r] = fexp2(s[r]);
      lsum += (((s[0] + s[1]) + (s[2] + s[3])) + ((s[4] + s[5]) + (s[6] + s[7])))
            + (((s[8] + s[9]) + (s[10] + s[11])) + ((s[12] + s[13]) + (s[14] + s[15])));

      // ---- pack P -> bf16 words; 2-shfl exchange (each side sends what the
      //      partner needs: hi=0 wants partner w0,w1; hi=1 wants partner w2,w3)
      __builtin_amdgcn_s_setprio(1);
      #pragma unroll
      for (int u = 0; u < 2; ++u) {
        const unsigned w0 = cvtpk(s[8*u + 0], s[8*u + 1]);
        const unsigned w1 = cvtpk(s[8*u + 2], s[8*u + 3]);
        const unsigned w2 = cvtpk(s[8*u + 4], s[8*u + 5]);
        const unsigned w3 = cvtpk(s[8*u + 6], s[8*u + 7]);
        const unsigned t0 = hi ? w0 : w2;
        const unsigned t1 = hi ? w1 : w3;
        const unsigned r0 = (unsigned)__shfl_xor((int)t0, 32);
        const unsigned r1 = (unsigned)__shfl_xor((int)t1, 32);
        u32x4 fw;
        fw[0] = hi ? r0 : w0;
        fw[1] = hi ? r1 : w1;
        fw[2] = hi ? w2 : r0;
        fw[3] = hi ? w3 : r1;
        bf16x8 pf = __builtin_bit_cast(bf16x8, fw);
        const int ksl = 2 * th + u;
        bf16x8 vf0 = (ksl == 0) ? vfa0 : (ksl == 1) ? vfb0 : (ksl == 2) ? vfc0 : vfd0;
        bf16x8 vf1 = (ksl == 0) ? vfa1 : (ksl == 1) ? vfb1 : (ksl == 2) ? vfc1 : vfd1;
        acc0 = mfma32(vf0, pf, acc0);
        acc1 = mfma32(vf1, pf, acc1);
      }
      __builtin_amdgcn_s_setprio(0);
    }

    __syncthreads();   // drains vmcnt (staging) + lgkm; flips buffers safely
  }

  // ---- cross-wave merge of the two kv-halves (exact online-softmax merge) ----
  // First merge lsum across the lane pair (l, l+32) sharing this q row.
  lsum += __shfl_xor(lsum, 32);

  if (kh2 == 1) {
    // upper waves publish partials: 16+16 acc + lsum + mr, stride 35 f32 (bank-clean)
    float* dst = &mg[(qw * 64 + lane) * 35];
    #pragma unroll
    for (int r = 0; r < 16; r++) dst[r] = acc0[r];
    #pragma unroll
    for (int r = 0; r < 16; r++) dst[16 + r] = acc1[r];
    dst[32] = lsum; dst[33] = mr;
  }
  __syncthreads();
  if (kh2 == 0) {
    const float* src = &mg[(qw * 64 + lane) * 35];
    const float lsb = src[32], mrb = src[33];
    const float M  = fmaxf(mr, mrb);
    const float wa = fexp2(mr - M), wb = fexp2(mrb - M);
    const float inv = 1.0f / (lsum * wa + lsb * wb);
    const float fa = wa * inv, fb = wb * inv;

    bf16* orow = o + ((size_t)(b * SEQ + qr + l31)) * D_MODEL + h * 64 + hi * 4;
    #pragma unroll
    for (int g = 0; g < 4; g++) {
      bf16x4 o0, o1;
      #pragma unroll
      for (int e = 0; e < 4; e++) {
        o0[e] = (bf16)(acc0[4*g + e] * fa + src[4*g + e] * fb);
        o1[e] = (bf16)(acc1[4*g + e] * fa + src[16 + 4*g + e] * fb);
      }
      *(bf16x4*)&orow[8 * g]      = o0;   // d = 8g + 4hi + e
      *(bf16x4*)&orow[32 + 8 * g] = o1;   // d = 32 + 8g + 4hi + e
    }
  }
}

// ---------------- launch ----------------

extern "C" void kernel_launch(void* const* d_in, const int* in_sizes, int n_in,
                              void* d_out, int out_size, void* d_ws, size_t ws_size,
                              hipStream_t stream) {
  const float* x      = (const float*)d_in[0];
  const float* w_qkv  = (const float*)d_in[1];
  const float* w_proj = (const float*)d_in[2];
  float* outf = (float*)d_out;

  bf16* xb    = (bf16*)d_ws;                                 // 4096*1024
  bf16* wqkvT = xb    + (size_t)MROWS * D_MODEL;             // 3072*1024
  bf16* wpT   = wqkvT + (size_t)3 * D_MODEL * D_MODEL;       // 1024*1024
  bf16* qb    = wpT   + (size_t)D_MODEL * D_MODEL;           // 32*2048*64
  bf16* kb    = qb    + (size_t)BHTOT * SEQ * DHEAD;
  bf16* vtb   = kb    + (size_t)BHTOT * SEQ * DHEAD;         // [BH][64][SEQ]
  bf16* ob    = xb;   // alias: xb dead after GEMM1

  dim3 tb(32, 8);

  cast_f32_bf16<<<(MROWS * D_MODEL / 4 + 255) / 256, 256, 0, stream>>>(
      x, xb, MROWS * D_MODEL / 4);
  tcast<<<dim3(3 * D_MODEL / 32, D_MODEL / 32), tb, 0, stream>>>(
      w_qkv, wqkvT, D_MODEL, 3 * D_MODEL);
  tcast<<<dim3(D_MODEL / 32, D_MODEL / 32), tb, 0, stream>>>(
      w_proj, wpT, D_MODEL, D_MODEL);

  gemm_bt<0><<<dim3(3 * D_MODEL / 128, MROWS / 128), 256, 0, stream>>>(
      xb, wqkvT, D_MODEL, 3 * D_MODEL, qb, kb, vtb, nullptr, nullptr);

  attn_kernel<<<dim3(SEQ / 128, BHTOT), 512, 0, stream>>>(qb, kb, vtb, ob);

  gemm_bt<1><<<dim3(D_MODEL / 128, MROWS / 128), 256, 0, stream>>>(
      ob, wpT, D_MODEL, D_MODEL, nullptr, nullptr, nullptr, x, outf);
}

// Round 11
// 152.364 us; speedup vs baseline: 1.2613x; 1.2613x over previous
//
#include <hip/hip_runtime.h>
#include <hip/hip_bf16.h>
#include <cstdint>
#include <cstddef>

typedef __bf16 bf16;
typedef __attribute__((ext_vector_type(4))) float f32x4;
typedef __attribute__((ext_vector_type(16))) float f32x16;
typedef __attribute__((ext_vector_type(8))) __bf16 bf16x8;
typedef __attribute__((ext_vector_type(4))) __bf16 bf16x4;
typedef __attribute__((ext_vector_type(4))) unsigned int u32x4;

#define D_MODEL 1024
#define NHEADS  16
#define DHEAD   64
#define SEQ     2048
#define BATCH   2
#define MROWS   (BATCH*SEQ)   /* 4096 */
#define BHTOT   (BATCH*NHEADS) /* 32 */

// 0.125 (1/sqrt(64)) * log2(e): fold into q so softmax uses exp2
#define QSCALE 0.18033688011112042f
// defer-max threshold in log2 units (HK's THR=8 nats * log2e)
#define DEFER_THR 11.5f

__device__ __forceinline__ void gload16(const bf16* g, bf16* l) {
  __builtin_amdgcn_global_load_lds(
      (const __attribute__((address_space(1))) void*)g,
      (__attribute__((address_space(3))) void*)l, 16, 0, 0);
}

__device__ __forceinline__ f32x4 mfma16(bf16x8 a, bf16x8 b, f32x4 c) {
  return __builtin_amdgcn_mfma_f32_16x16x32_bf16(a, b, c, 0, 0, 0);
}

__device__ __forceinline__ f32x16 mfma32(bf16x8 a, bf16x8 b, f32x16 c) {
  return __builtin_amdgcn_mfma_f32_32x32x16_bf16(a, b, c, 0, 0, 0);
}

// raw v_exp_f32 (skip libm range-fixup; |x| well within range here)
__device__ __forceinline__ float fexp2(float x) {
#if __has_builtin(__builtin_amdgcn_exp2f)
  return __builtin_amdgcn_exp2f(x);
#else
  float r; asm("v_exp_f32 %0, %1" : "=v"(r) : "v"(x)); return r;
#endif
}

// pack two f32 -> one u32 of 2 bf16 (lo = first arg)
__device__ __forceinline__ unsigned cvtpk(float lo, float hi) {
  unsigned r;
  asm("v_cvt_pk_bf16_f32 %0, %1, %2" : "=v"(r) : "v"(lo), "v"(hi));
  return r;
}

// ---------------- prep kernels ----------------

__global__ void cast_f32_bf16(const float* __restrict__ in, bf16* __restrict__ out, int n4) {
  int i = blockIdx.x * blockDim.x + threadIdx.x;
  if (i >= n4) return;
  float4 v = ((const float4*)in)[i];
  bf16x4 o;
  o[0] = (bf16)v.x; o[1] = (bf16)v.y; o[2] = (bf16)v.z; o[3] = (bf16)v.w;
  ((bf16x4*)out)[i] = o;
}

// in [R][C] fp32  ->  out [C][R] bf16
__global__ void tcast(const float* __restrict__ in, bf16* __restrict__ out, int R, int C) {
  __shared__ float t[32][33];
  int c0 = blockIdx.x * 32, r0 = blockIdx.y * 32;
  int tx = threadIdx.x, ty = threadIdx.y;
  #pragma unroll
  for (int i = 0; i < 4; i++)
    t[ty + i*8][tx] = in[(size_t)(r0 + ty + i*8) * C + c0 + tx];
  __syncthreads();
  #pragma unroll
  for (int i = 0; i < 4; i++)
    out[(size_t)(c0 + ty + i*8) * R + r0 + tx] = (bf16)t[tx][ty + i*8];
}

// ---------------- GEMM: C[M][N] = A[M][K](bf16) * Bt[N][K](bf16)^T ----------------
// BK=64, XOR-swizzled LDS (pre-swizzled global source + swizzled ds_read, rule 21).
// EPI 0: scatter q/k head-major (q scaled by QSCALE) and v directly TRANSPOSED
//        into vt[BH][64][SEQ]; EPI 1: fp32 out = acc + x.

template <int EPI>
__global__ __launch_bounds__(256, 3) void gemm_bt(
    const bf16* __restrict__ A, const bf16* __restrict__ Bt, int K, int N,
    bf16* __restrict__ qb, bf16* __restrict__ kb, bf16* __restrict__ vtb,
    const float* __restrict__ xres, float* __restrict__ outf) {
  __shared__ alignas(16) bf16 As[128 * 64];
  __shared__ alignas(16) bf16 Bs[128 * 64];
  const int tid = threadIdx.x;
  const int wave = tid >> 6, lane = tid & 63;
  const int wr = wave >> 1, wc = wave & 1;
  const int m0 = blockIdx.y * 128, n0 = blockIdx.x * 128;
  const int srow = lane >> 3;                    // row within 8-row chunk
  const int scol = ((lane & 7) ^ srow) * 8;      // pre-swizzled source column
  const int lr16 = lane & 15, lg = lane >> 4;
  const int rsw = (lr16 & 7) << 4;
  const int cA = (lg * 16) ^ rsw;
  const int cB = (64 + lg * 16) ^ rsw;
  const char* aP = (const char*)As + (wr*64 + lr16) * 128;
  const char* bP = (const char*)Bs + (wc*64 + lr16) * 128;

  f32x4 acc[4][4];
  #pragma unroll
  for (int m = 0; m < 4; m++)
    #pragma unroll
    for (int n = 0; n < 4; n++) acc[m][n] = (f32x4)0.0f;

  for (int k0 = 0; k0 < K; k0 += 64) {
    #pragma unroll
    for (int j = 0; j < 4; j++) {
      const int c = wave * 4 + j;                // 8-row chunk index (0..15)
      gload16(A  + (size_t)(m0 + c*8 + srow) * K + k0 + scol, &As[c * 512]);
      gload16(Bt + (size_t)(n0 + c*8 + srow) * K + k0 + scol, &Bs[c * 512]);
    }
    __syncthreads();
    bf16x8 af[4][2], bfr[4][2];
    #pragma unroll
    for (int m = 0; m < 4; m++) {
      af[m][0] = *(const bf16x8*)(aP + m*2048 + cA);
      af[m][1] = *(const bf16x8*)(aP + m*2048 + cB);
    }
    #pragma unroll
    for (int n = 0; n < 4; n++) {
      bfr[n][0] = *(const bf16x8*)(bP + n*2048 + cA);
      bfr[n][1] = *(const bf16x8*)(bP + n*2048 + cB);
    }
    #pragma unroll
    for (int m = 0; m < 4; m++)
      #pragma unroll
      for (int n = 0; n < 4; n++) {
        acc[m][n] = mfma16(af[m][0], bfr[n][0], acc[m][n]);
        acc[m][n] = mfma16(af[m][1], bfr[n][1], acc[m][n]);
      }
    __syncthreads();
  }

  #pragma unroll
  for (int n = 0; n < 4; n++) {
    const int colg = n0 + wc*64 + n*16 + lr16;
    if (EPI == 0) {
      const int which = colg >> 10;           // 0=q 1=k 2=v
      const int win = colg & 1023;
      const int h = win >> 6, d = win & 63;
      #pragma unroll
      for (int m = 0; m < 4; m++) {
        const int rowg0 = m0 + wr*64 + m*16 + lg*4;
        #pragma unroll
        for (int j = 0; j < 4; j++) {
          const int rowg = rowg0 + j;
          const int b = rowg >> 11, r = rowg & 2047;
          const int bh = (b << 4) + h;
          if (which == 2) {
            // v -> transposed layout vt[bh][d][r]
            vtb[((size_t)bh * DHEAD + d) * SEQ + r] = (bf16)acc[m][n][j];
          } else {
            bf16* dst = (which == 0) ? qb : kb;
            const float sc = (which == 0) ? QSCALE : 1.0f;
            dst[((size_t)bh * SEQ + r) * DHEAD + d] = (bf16)(acc[m][n][j] * sc);
          }
        }
      }
    } else {
      #pragma unroll
      for (int m = 0; m < 4; m++) {
        const int rowg0 = m0 + wr*64 + m*16 + lg*4;
        #pragma unroll
        for (int j = 0; j < 4; j++) {
          const size_t idx = (size_t)(rowg0 + j) * N + colg;
          outf[idx] = acc[m][n][j] + xres[idx];
        }
      }
    }
  }
}

// ---------------- flash attention: 32x32x16 MFMA, in-block KV split ----------------
// 512-thread block = 8 waves: wave w -> (q-subtile qw = w&3 [32 rows], kv-half
// kh2 = w>>2 [1024 kv]). K is LDS-staged (double-buffered, swizzled) per kv-half;
// V is read DIRECT from global (vt[bh][d][kv]: contiguous 16B lane loads,
// L2-resident) — but only the CURRENT 32-kv half's 4 fragments are live at once
// (R10 lesson: holding all 8 across both halves pushed peak VGPR past the
// 128-cap -> scratch spill, +21MB WRITE_SIZE). P stays reg-resident: cvtpk +
// 2x shfl_xor(32). Partner kv-halves merge online-softmax partials via LDS.
__global__ __launch_bounds__(512, 4) void attn_kernel(
    const bf16* __restrict__ q, const bf16* __restrict__ k,
    const bf16* __restrict__ vt, bf16* __restrict__ o) {
  // staging: [kh2:16KB][buf:8KB] bf16 K tiles; merge area (35840B) aliases after loop
  __shared__ alignas(16) char smraw[36864];
  bf16* kvb = (bf16*)smraw;
  float* mg = (float*)smraw;

  const int tid = threadIdx.x;
  const int wave = tid >> 6, lane = tid & 63;
  const int qw = wave & 3, kh2 = wave >> 2;
  const int l31 = lane & 31, hi = lane >> 5;
  const int bh = blockIdx.y;
  const int b = bh >> 4, h = bh & 15;
  const int qr = blockIdx.x * 128 + qw * 32;
  const bf16* kh = k  + (size_t)bh * SEQ * DHEAD;
  const bf16* vh = vt + (size_t)bh * DHEAD * SEQ;

  // K staging: within a kv-half, wave qw covers rows [qw*16, qw*16+16) of the 64-row tile
  const int srow = lane >> 3;
  const int scol = ((lane & 7) ^ srow) * 8;
  const bf16* kg = kh + (size_t)(kh2 * 1024 + qw * 16 + srow) * DHEAD + scol;
  bf16* ldsK0 = kvb + kh2 * 8192 +        qw * 1024;
  bf16* ldsK1 = kvb + kh2 * 8192 + 4096 + qw * 1024;

  // V direct-read bases: d-row = l31 (acc0) / 32+l31 (acc1), col = kv
  const bf16* v0p = vh + (size_t)l31 * SEQ + kh2 * 1024 + hi * 8;
  const bf16* v1p = vh + (size_t)(32 + l31) * SEQ + kh2 * 1024 + hi * 8;

  // Q fragments (B operand): lane holds q-row (qr+l31), k = ks*16 + hi*8 + j
  const bf16* qrow = q + (size_t)bh * SEQ * DHEAD + (size_t)(qr + l31) * DHEAD;
  bf16x8 qf[4];
  #pragma unroll
  for (int ks = 0; ks < 4; ks++)
    qf[ks] = *(const bf16x8*)&qrow[ks * 16 + hi * 8];

  float mr = 0.0f, lsum = 0.0f;
  f32x16 acc0 = (f32x16)0.0f, acc1 = (f32x16)0.0f;  // O^T d-tiles 0..31 / 32..63

  // hoisted K read offsets: row = l31 (+32 for half 1), col slot XOR-swizzled by row&7
  const int rsw = (lane & 7) << 4;
  const int rowoff = l31 * 128;
  int cofs[4];
  #pragma unroll
  for (int ks = 0; ks < 4; ks++) cofs[ks] = (ks * 32 + hi * 16) ^ rsw;
  const char* kr0 = (const char*)(kvb + kh2 * 8192) + rowoff;
  const char* kr1 = (const char*)(kvb + kh2 * 8192 + 4096) + rowoff;

  // prologue: stage K tile 0 into buf 0
  gload16(kg, ldsK0); gload16(kg + 8 * DHEAD, ldsK0 + 512);
  kg += 64 * DHEAD;
  __syncthreads();

  const int NT = 1024 / 64;   // 16 iters per kv-half
  for (int t = 0; t < NT; ++t) {
    // stage next K tile into the other buffer (wave-uniform selects, no arrays)
    bf16* dK = (t & 1) ? ldsK0 : ldsK1;
    if (t + 1 < NT) {
      gload16(kg, dK); gload16(kg + 8 * DHEAD, dK + 512);
      kg += 64 * DHEAD;
    }
    const char* kr = (t & 1) ? kr1 : kr0;

    // two 32-kv halves, fully sequential (low register peak)
    #pragma unroll
    for (int th = 0; th < 2; ++th) {
      const int toff = th * 4096;       // +32 kv rows in K tile
      const int kvh = t * 64 + th * 32; // global kv offset of this half

      // issue this half's 4 V fragments now; L2 latency hides under QK^T+softmax
      bf16x8 vA0 = *(const bf16x8*)(v0p + kvh);
      bf16x8 vA1 = *(const bf16x8*)(v1p + kvh);
      bf16x8 vB0 = *(const bf16x8*)(v0p + kvh + 16);
      bf16x8 vB1 = *(const bf16x8*)(v1p + kvh + 16);

      // ---- QK^T (swapped): one 32x32 S^T tile, C-init = -mr
      const float nmr = -mr;
      f32x16 s = (f32x16)nmr;
      __builtin_amdgcn_s_setprio(1);
      #pragma unroll
      for (int ks = 0; ks < 4; ks++) {
        bf16x8 kf = *(const bf16x8*)(kr + toff + cofs[ks]);
        s = mfma32(kf, qf[ks], s);
      }
      __builtin_amdgcn_s_setprio(0);

      // ---- defer-max: tree max over the lane's 16 scores
      const float a0 = fmaxf(fmaxf(s[0], s[1]), fmaxf(s[2], s[3]));
      const float a1 = fmaxf(fmaxf(s[4], s[5]), fmaxf(s[6], s[7]));
      const float a2 = fmaxf(fmaxf(s[8], s[9]), fmaxf(s[10], s[11]));
      const float a3 = fmaxf(fmaxf(s[12], s[13]), fmaxf(s[14], s[15]));
      const float lmax = fmaxf(fmaxf(a0, a1), fmaxf(a2, a3));

      if (!__all(lmax <= DEFER_THR)) {       // rare: rescale
        float mx = fmaxf(lmax, __shfl_xor(lmax, 32));
        mx = fmaxf(mx, 0.0f);
        const float corr = fexp2(-mx);
        lsum *= corr;
        acc0 *= corr; acc1 *= corr;
        mr += mx;
        #pragma unroll
        for (int r = 0; r < 16; r++) s[r] -= mx;
      }

      // ---- exp2 + per-lane partial sum
      #pragma unroll
      for (int r = 0; r < 16; r++) s[r] = fexp2(s[r]);
      lsum += (((s[0] + s[1]) + (s[2] + s[3])) + ((s[4] + s[5]) + (s[6] + s[7])))
            + (((s[8] + s[9]) + (s[10] + s[11])) + ((s[12] + s[13]) + (s[14] + s[15])));

      // ---- pack P -> bf16 words; 2-shfl exchange (each side sends what the
      //      partner needs: hi=0 wants partner w0,w1; hi=1 wants partner w2,w3)
      __builtin_amdgcn_s_setprio(1);
      #pragma unroll
      for (int u = 0; u < 2; ++u) {
        const unsigned w0 = cvtpk(s[8*u + 0], s[8*u + 1]);
        const unsigned w1 = cvtpk(s[8*u + 2], s[8*u + 3]);
        const unsigned w2 = cvtpk(s[8*u + 4], s[8*u + 5]);
        const unsigned w3 = cvtpk(s[8*u + 6], s[8*u + 7]);
        const unsigned t0 = hi ? w0 : w2;
        const unsigned t1 = hi ? w1 : w3;
        const unsigned r0 = (unsigned)__shfl_xor((int)t0, 32);
        const unsigned r1 = (unsigned)__shfl_xor((int)t1, 32);
        u32x4 fw;
        fw[0] = hi ? r0 : w0;
        fw[1] = hi ? r1 : w1;
        fw[2] = hi ? w2 : r0;
        fw[3] = hi ? w3 : r1;
        bf16x8 pf = __builtin_bit_cast(bf16x8, fw);
        bf16x8 vf0 = u ? vB0 : vA0;
        bf16x8 vf1 = u ? vB1 : vA1;
        acc0 = mfma32(vf0, pf, acc0);
        acc1 = mfma32(vf1, pf, acc1);
      }
      __builtin_amdgcn_s_setprio(0);
    }

    __syncthreads();   // drains vmcnt (staging) + lgkm; flips buffers safely
  }

  // ---- cross-wave merge of the two kv-halves (exact online-softmax merge) ----
  // First merge lsum across the lane pair (l, l+32) sharing this q row.
  lsum += __shfl_xor(lsum, 32);

  if (kh2 == 1) {
    // upper waves publish partials: 16+16 acc + lsum + mr, stride 35 f32 (bank-clean)
    float* dst = &mg[(qw * 64 + lane) * 35];
    #pragma unroll
    for (int r = 0; r < 16; r++) dst[r] = acc0[r];
    #pragma unroll
    for (int r = 0; r < 16; r++) dst[16 + r] = acc1[r];
    dst[32] = lsum; dst[33] = mr;
  }
  __syncthreads();
  if (kh2 == 0) {
    const float* src = &mg[(qw * 64 + lane) * 35];
    const float lsb = src[32], mrb = src[33];
    const float M  = fmaxf(mr, mrb);
    const float wa = fexp2(mr - M), wb = fexp2(mrb - M);
    const float inv = 1.0f / (lsum * wa + lsb * wb);
    const float fa = wa * inv, fb = wb * inv;

    bf16* orow = o + ((size_t)(b * SEQ + qr + l31)) * D_MODEL + h * 64 + hi * 4;
    #pragma unroll
    for (int g = 0; g < 4; g++) {
      bf16x4 o0, o1;
      #pragma unroll
      for (int e = 0; e < 4; e++) {
        o0[e] = (bf16)(acc0[4*g + e] * fa + src[4*g + e] * fb);
        o1[e] = (bf16)(acc1[4*g + e] * fa + src[16 + 4*g + e] * fb);
      }
      *(bf16x4*)&orow[8 * g]      = o0;   // d = 8g + 4hi + e
      *(bf16x4*)&orow[32 + 8 * g] = o1;   // d = 32 + 8g + 4hi + e
    }
  }
}

// ---------------- launch ----------------

extern "C" void kernel_launch(void* const* d_in, const int* in_sizes, int n_in,
                              void* d_out, int out_size, void* d_ws, size_t ws_size,
                              hipStream_t stream) {
  const float* x      = (const float*)d_in[0];
  const float* w_qkv  = (const float*)d_in[1];
  const float* w_proj = (const float*)d_in[2];
  float* outf = (float*)d_out;

  bf16* xb    = (bf16*)d_ws;                                 // 4096*1024
  bf16* wqkvT = xb    + (size_t)MROWS * D_MODEL;             // 3072*1024
  bf16* wpT   = wqkvT + (size_t)3 * D_MODEL * D_MODEL;       // 1024*1024
  bf16* qb    = wpT   + (size_t)D_MODEL * D_MODEL;           // 32*2048*64
  bf16* kb    = qb    + (size_t)BHTOT * SEQ * DHEAD;
  bf16* vtb   = kb    + (size_t)BHTOT * SEQ * DHEAD;         // [BH][64][SEQ]
  bf16* ob    = xb;   // alias: xb dead after GEMM1

  dim3 tb(32, 8);

  cast_f32_bf16<<<(MROWS * D_MODEL / 4 + 255) / 256, 256, 0, stream>>>(
      x, xb, MROWS * D_MODEL / 4);
  tcast<<<dim3(3 * D_MODEL / 32, D_MODEL / 32), tb, 0, stream>>>(
      w_qkv, wqkvT, D_MODEL, 3 * D_MODEL);
  tcast<<<dim3(D_MODEL / 32, D_MODEL / 32), tb, 0, stream>>>(
      w_proj, wpT, D_MODEL, D_MODEL);

  gemm_bt<0><<<dim3(3 * D_MODEL / 128, MROWS / 128), 256, 0, stream>>>(
      xb, wqkvT, D_MODEL, 3 * D_MODEL, qb, kb, vtb, nullptr, nullptr);

  attn_kernel<<<dim3(SEQ / 128, BHTOT), 512, 0, stream>>>(qb, kb, vtb, ob);

  gemm_bt<1><<<dim3(D_MODEL / 128, MROWS / 128), 256, 0, stream>>>(
      ob, wpT, D_MODEL, D_MODEL, nullptr, nullptr, nullptr, x, outf);
}

// Round 12
// 131.888 us; speedup vs baseline: 1.4571x; 1.1553x over previous
//
#include <hip/hip_runtime.h>
#include <hip/hip_bf16.h>
#include <cstdint>
#include <cstddef>

typedef __bf16 bf16;
typedef __attribute__((ext_vector_type(4))) float f32x4;
typedef __attribute__((ext_vector_type(16))) float f32x16;
typedef __attribute__((ext_vector_type(8))) __bf16 bf16x8;
typedef __attribute__((ext_vector_type(4))) __bf16 bf16x4;
typedef __attribute__((ext_vector_type(4))) unsigned int u32x4;

#define D_MODEL 1024
#define NHEADS  16
#define DHEAD   64
#define SEQ     2048
#define BATCH   2
#define MROWS   (BATCH*SEQ)   /* 4096 */
#define BHTOT   (BATCH*NHEADS) /* 32 */

// 0.125 (1/sqrt(64)) * log2(e): fold into q so softmax uses exp2
#define QSCALE 0.18033688011112042f
// defer-max threshold in log2 units (HK's THR=8 nats * log2e)
#define DEFER_THR 11.5f

__device__ __forceinline__ void gload16(const bf16* g, bf16* l) {
  __builtin_amdgcn_global_load_lds(
      (const __attribute__((address_space(1))) void*)g,
      (__attribute__((address_space(3))) void*)l, 16, 0, 0);
}

__device__ __forceinline__ f32x4 mfma16(bf16x8 a, bf16x8 b, f32x4 c) {
  return __builtin_amdgcn_mfma_f32_16x16x32_bf16(a, b, c, 0, 0, 0);
}

__device__ __forceinline__ f32x16 mfma32(bf16x8 a, bf16x8 b, f32x16 c) {
  return __builtin_amdgcn_mfma_f32_32x32x16_bf16(a, b, c, 0, 0, 0);
}

// raw v_exp_f32 (skip libm range-fixup; |x| well within range here)
__device__ __forceinline__ float fexp2(float x) {
#if __has_builtin(__builtin_amdgcn_exp2f)
  return __builtin_amdgcn_exp2f(x);
#else
  float r; asm("v_exp_f32 %0, %1" : "=v"(r) : "v"(x)); return r;
#endif
}

// pack two f32 -> one u32 of 2 bf16 (lo = first arg)
__device__ __forceinline__ unsigned cvtpk(float lo, float hi) {
  unsigned r;
  asm("v_cvt_pk_bf16_f32 %0, %1, %2" : "=v"(r) : "v"(lo), "v"(hi));
  return r;
}

// ---------------- prep kernels ----------------

__global__ void cast_f32_bf16(const float* __restrict__ in, bf16* __restrict__ out, int n4) {
  int i = blockIdx.x * blockDim.x + threadIdx.x;
  if (i >= n4) return;
  float4 v = ((const float4*)in)[i];
  bf16x4 o;
  o[0] = (bf16)v.x; o[1] = (bf16)v.y; o[2] = (bf16)v.z; o[3] = (bf16)v.w;
  ((bf16x4*)out)[i] = o;
}

// in [R][C] fp32  ->  out [C][R] bf16
__global__ void tcast(const float* __restrict__ in, bf16* __restrict__ out, int R, int C) {
  __shared__ float t[32][33];
  int c0 = blockIdx.x * 32, r0 = blockIdx.y * 32;
  int tx = threadIdx.x, ty = threadIdx.y;
  #pragma unroll
  for (int i = 0; i < 4; i++)
    t[ty + i*8][tx] = in[(size_t)(r0 + ty + i*8) * C + c0 + tx];
  __syncthreads();
  #pragma unroll
  for (int i = 0; i < 4; i++)
    out[(size_t)(c0 + ty + i*8) * R + r0 + tx] = (bf16)t[tx][ty + i*8];
}

// ---------------- GEMM: C[M][N] = A[M][K](bf16) * Bt[N][K](bf16)^T ----------------
// BK=64, XOR-swizzled LDS (pre-swizzled global source + swizzled ds_read, rule 21).
// XCD-aware bijective block swizzle (nwg % 8 == 0 for both instantiations).
// EPI 0: scatter q/k head-major (q scaled by QSCALE) and v directly TRANSPOSED
//        into vt[BH][64][SEQ]; EPI 1: fp32 out = acc + x.

template <int EPI>
__global__ __launch_bounds__(256, 3) void gemm_bt(
    const bf16* __restrict__ A, const bf16* __restrict__ Bt, int K, int N,
    bf16* __restrict__ qb, bf16* __restrict__ kb, bf16* __restrict__ vtb,
    const float* __restrict__ xres, float* __restrict__ outf) {
  __shared__ alignas(16) bf16 As[128 * 64];
  __shared__ alignas(16) bf16 Bs[128 * 64];
  const int tid = threadIdx.x;
  const int wave = tid >> 6, lane = tid & 63;
  const int wr = wave >> 1, wc = wave & 1;

  // XCD swizzle: consecutive work-tiles land on the same XCD's L2
  const int nwg = gridDim.x * gridDim.y;
  const int id = blockIdx.y * gridDim.x + blockIdx.x;
  const int swz = (id & 7) * (nwg >> 3) + (id >> 3);
  const int bx = swz % gridDim.x, by = swz / gridDim.x;
  const int m0 = by * 128, n0 = bx * 128;

  const int srow = lane >> 3;                    // row within 8-row chunk
  const int scol = ((lane & 7) ^ srow) * 8;      // pre-swizzled source column
  const int lr16 = lane & 15, lg = lane >> 4;
  const int rsw = (lr16 & 7) << 4;
  const int cA = (lg * 16) ^ rsw;
  const int cB = (64 + lg * 16) ^ rsw;
  const char* aP = (const char*)As + (wr*64 + lr16) * 128;
  const char* bP = (const char*)Bs + (wc*64 + lr16) * 128;

  f32x4 acc[4][4];
  #pragma unroll
  for (int m = 0; m < 4; m++)
    #pragma unroll
    for (int n = 0; n < 4; n++) acc[m][n] = (f32x4)0.0f;

  for (int k0 = 0; k0 < K; k0 += 64) {
    #pragma unroll
    for (int j = 0; j < 4; j++) {
      const int c = wave * 4 + j;                // 8-row chunk index (0..15)
      gload16(A  + (size_t)(m0 + c*8 + srow) * K + k0 + scol, &As[c * 512]);
      gload16(Bt + (size_t)(n0 + c*8 + srow) * K + k0 + scol, &Bs[c * 512]);
    }
    __syncthreads();
    bf16x8 af[4][2], bfr[4][2];
    #pragma unroll
    for (int m = 0; m < 4; m++) {
      af[m][0] = *(const bf16x8*)(aP + m*2048 + cA);
      af[m][1] = *(const bf16x8*)(aP + m*2048 + cB);
    }
    #pragma unroll
    for (int n = 0; n < 4; n++) {
      bfr[n][0] = *(const bf16x8*)(bP + n*2048 + cA);
      bfr[n][1] = *(const bf16x8*)(bP + n*2048 + cB);
    }
    #pragma unroll
    for (int m = 0; m < 4; m++)
      #pragma unroll
      for (int n = 0; n < 4; n++) {
        acc[m][n] = mfma16(af[m][0], bfr[n][0], acc[m][n]);
        acc[m][n] = mfma16(af[m][1], bfr[n][1], acc[m][n]);
      }
    __syncthreads();
  }

  #pragma unroll
  for (int n = 0; n < 4; n++) {
    const int colg = n0 + wc*64 + n*16 + lr16;
    if (EPI == 0) {
      const int which = colg >> 10;           // 0=q 1=k 2=v
      const int win = colg & 1023;
      const int h = win >> 6, d = win & 63;
      #pragma unroll
      for (int m = 0; m < 4; m++) {
        const int rowg0 = m0 + wr*64 + m*16 + lg*4;
        #pragma unroll
        for (int j = 0; j < 4; j++) {
          const int rowg = rowg0 + j;
          const int b = rowg >> 11, r = rowg & 2047;
          const int bh = (b << 4) + h;
          if (which == 2) {
            // v -> transposed layout vt[bh][d][r]
            vtb[((size_t)bh * DHEAD + d) * SEQ + r] = (bf16)acc[m][n][j];
          } else {
            bf16* dst = (which == 0) ? qb : kb;
            const float sc = (which == 0) ? QSCALE : 1.0f;
            dst[((size_t)bh * SEQ + r) * DHEAD + d] = (bf16)(acc[m][n][j] * sc);
          }
        }
      }
    } else {
      #pragma unroll
      for (int m = 0; m < 4; m++) {
        const int rowg0 = m0 + wr*64 + m*16 + lg*4;
        #pragma unroll
        for (int j = 0; j < 4; j++) {
          const size_t idx = (size_t)(rowg0 + j) * N + colg;
          outf[idx] = acc[m][n][j] + xres[idx];
        }
      }
    }
  }
}

// ---------------- flash attention: 32x32x16 MFMA, in-block KV split ----------------
// R9 structure (best measured: 58.3 us): 512-thread block = 8 waves, wave w ->
// (q-subtile qw = w&3 [32 rows], kv-half kh2 = w>>2 [1024 kv]). K AND V both
// LDS-staged (double-buffered, swizzled) per kv-half (V-direct-from-global was
// tried in R10/R11: 64 scattered cache lines per V-load -> net regression).
// P reg-resident: cvtpk + 2-shfl exchange (validated R10/R11, equivalent to the
// 4-shfl form). Partner kv-halves merge online-softmax partials via LDS.
__global__ __launch_bounds__(512, 2) void attn_kernel(
    const bf16* __restrict__ q, const bf16* __restrict__ k,
    const bf16* __restrict__ vt, bf16* __restrict__ o) {
  // [kh2:32KB][buf:16KB][K/V:8KB] bf16 staging; merge area aliases after final barrier
  __shared__ alignas(16) char smraw[65536];
  bf16* kvb = (bf16*)smraw;
  float* mg = (float*)smraw;

  const int tid = threadIdx.x;
  const int wave = tid >> 6, lane = tid & 63;
  const int qw = wave & 3, kh2 = wave >> 2;
  const int l31 = lane & 31, hi = lane >> 5;
  const int bh = blockIdx.y;
  const int b = bh >> 4, h = bh & 15;
  const int qr = blockIdx.x * 128 + qw * 32;
  const bf16* kh = k  + (size_t)bh * SEQ * DHEAD;
  const bf16* vh = vt + (size_t)bh * DHEAD * SEQ;

  // staging: within a kv-half, wave qw covers rows [qw*16, qw*16+16) of the 64-row tile
  const int srow = lane >> 3;
  const int scol = ((lane & 7) ^ srow) * 8;
  const bf16* kg = kh + (size_t)(kh2 * 1024 + qw * 16 + srow) * DHEAD + scol;
  const bf16* vg = vh + (size_t)(qw * 16 + srow) * SEQ + kh2 * 1024 + scol;
  bf16* ldsK0 = kvb + kh2 * 16384 +        qw * 1024;
  bf16* ldsK1 = kvb + kh2 * 16384 + 8192 + qw * 1024;
  bf16* ldsV0 = kvb + kh2 * 16384 + 4096 +        qw * 1024;
  bf16* ldsV1 = kvb + kh2 * 16384 + 8192 + 4096 + qw * 1024;

  // Q fragments (B operand): lane holds q-row (qr+l31), k = ks*16 + hi*8 + j
  const bf16* qrow = q + (size_t)bh * SEQ * DHEAD + (size_t)(qr + l31) * DHEAD;
  bf16x8 qf[4];
  #pragma unroll
  for (int ks = 0; ks < 4; ks++)
    qf[ks] = *(const bf16x8*)&qrow[ks * 16 + hi * 8];

  float mr = 0.0f, lsum = 0.0f;
  f32x16 acc0 = (f32x16)0.0f, acc1 = (f32x16)0.0f;  // O^T d-tiles 0..31 / 32..63

  // hoisted read offsets: row = l31 (+32 for half 1), col slot XOR-swizzled by row&7
  const int rsw = (lane & 7) << 4;
  const int rowoff = l31 * 128;
  int cofs[4];
  #pragma unroll
  for (int ks = 0; ks < 4; ks++) cofs[ks] = (ks * 32 + hi * 16) ^ rsw;
  const char* kr0 = (const char*)(kvb + kh2 * 16384) + rowoff;
  const char* kr1 = (const char*)(kvb + kh2 * 16384 + 8192) + rowoff;
  const char* vr0 = (const char*)(kvb + kh2 * 16384 + 4096) + rowoff;
  const char* vr1 = (const char*)(kvb + kh2 * 16384 + 8192 + 4096) + rowoff;

  // prologue: stage tile 0 into buf 0
  gload16(kg, ldsK0); gload16(kg + 8 * DHEAD, ldsK0 + 512);
  gload16(vg, ldsV0); gload16(vg + 8 * SEQ,   ldsV0 + 512);
  kg += 64 * DHEAD; vg += 64;
  __syncthreads();

  const int NT = 1024 / 64;   // 16 iters per kv-half
  for (int t = 0; t < NT; ++t) {
    // stage next tile into the other buffer (wave-uniform selects, no arrays)
    bf16* dK = (t & 1) ? ldsK0 : ldsK1;
    bf16* dV = (t & 1) ? ldsV0 : ldsV1;
    if (t + 1 < NT) {
      gload16(kg, dK); gload16(kg + 8 * DHEAD, dK + 512);
      gload16(vg, dV); gload16(vg + 8 * SEQ,   dV + 512);
      kg += 64 * DHEAD; vg += 64;
    }
    const char* kr = (t & 1) ? kr1 : kr0;
    const char* vr = (t & 1) ? vr1 : vr0;

    // two 32-kv halves, fully sequential (low register peak)
    #pragma unroll
    for (int th = 0; th < 2; ++th) {
      const int toff = th * 4096;   // +32 kv rows in K tile

      // ---- QK^T (swapped): one 32x32 S^T tile, C-init = -mr
      const float nmr = -mr;
      f32x16 s = (f32x16)nmr;
      __builtin_amdgcn_s_setprio(1);
      #pragma unroll
      for (int ks = 0; ks < 4; ks++) {
        bf16x8 kf = *(const bf16x8*)(kr + toff + cofs[ks]);
        s = mfma32(kf, qf[ks], s);
      }
      __builtin_amdgcn_s_setprio(0);

      // ---- defer-max: tree max over the lane's 16 scores
      const float a0 = fmaxf(fmaxf(s[0], s[1]), fmaxf(s[2], s[3]));
      const float a1 = fmaxf(fmaxf(s[4], s[5]), fmaxf(s[6], s[7]));
      const float a2 = fmaxf(fmaxf(s[8], s[9]), fmaxf(s[10], s[11]));
      const float a3 = fmaxf(fmaxf(s[12], s[13]), fmaxf(s[14], s[15]));
      const float lmax = fmaxf(fmaxf(a0, a1), fmaxf(a2, a3));

      if (!__all(lmax <= DEFER_THR)) {       // rare: rescale
        float mx = fmaxf(lmax, __shfl_xor(lmax, 32));
        mx = fmaxf(mx, 0.0f);
        const float corr = fexp2(-mx);
        lsum *= corr;
        acc0 *= corr; acc1 *= corr;
        mr += mx;
        #pragma unroll
        for (int r = 0; r < 16; r++) s[r] -= mx;
      }

      // ---- exp2 + per-lane partial sum
      #pragma unroll
      for (int r = 0; r < 16; r++) s[r] = fexp2(s[r]);
      lsum += (((s[0] + s[1]) + (s[2] + s[3])) + ((s[4] + s[5]) + (s[6] + s[7])))
            + (((s[8] + s[9]) + (s[10] + s[11])) + ((s[12] + s[13]) + (s[14] + s[15])));

      // ---- pack P -> bf16 words; 2-shfl exchange (each side sends exactly what
      //      the partner needs: hi=0 wants partner w0,w1; hi=1 wants partner w2,w3)
      __builtin_amdgcn_s_setprio(1);
      #pragma unroll
      for (int u = 0; u < 2; ++u) {
        const unsigned w0 = cvtpk(s[8*u + 0], s[8*u + 1]);
        const unsigned w1 = cvtpk(s[8*u + 2], s[8*u + 3]);
        const unsigned w2 = cvtpk(s[8*u + 4], s[8*u + 5]);
        const unsigned w3 = cvtpk(s[8*u + 6], s[8*u + 7]);
        const unsigned t0 = hi ? w0 : w2;
        const unsigned t1 = hi ? w1 : w3;
        const unsigned r0 = (unsigned)__shfl_xor((int)t0, 32);
        const unsigned r1 = (unsigned)__shfl_xor((int)t1, 32);
        u32x4 fw;
        fw[0] = hi ? r0 : w0;
        fw[1] = hi ? r1 : w1;
        fw[2] = hi ? w2 : r0;
        fw[3] = hi ? w3 : r1;
        bf16x8 pf = __builtin_bit_cast(bf16x8, fw);
        const int ksl = 2 * th + u;
        bf16x8 vf0 = *(const bf16x8*)(vr + cofs[ksl]);
        bf16x8 vf1 = *(const bf16x8*)(vr + 4096 + cofs[ksl]);
        acc0 = mfma32(vf0, pf, acc0);
        acc1 = mfma32(vf1, pf, acc1);
      }
      __builtin_amdgcn_s_setprio(0);
    }

    __syncthreads();   // drains vmcnt (staging) + lgkm; flips buffers safely
  }

  // ---- cross-wave merge of the two kv-halves (exact online-softmax merge) ----
  // First merge lsum across the lane pair (l, l+32) sharing this q row.
  lsum += __shfl_xor(lsum, 32);

  if (kh2 == 1) {
    // upper waves publish partials: 16+16 acc + lsum + mr, stride 35 f32 (bank-clean)
    float* dst = &mg[(qw * 64 + lane) * 35];
    #pragma unroll
    for (int r = 0; r < 16; r++) dst[r] = acc0[r];
    #pragma unroll
    for (int r = 0; r < 16; r++) dst[16 + r] = acc1[r];
    dst[32] = lsum; dst[33] = mr;
  }
  __syncthreads();
  if (kh2 == 0) {
    const float* src = &mg[(qw * 64 + lane) * 35];
    const float lsb = src[32], mrb = src[33];
    const float M  = fmaxf(mr, mrb);
    const float wa = fexp2(mr - M), wb = fexp2(mrb - M);
    const float inv = 1.0f / (lsum * wa + lsb * wb);
    const float fa = wa * inv, fb = wb * inv;

    bf16* orow = o + ((size_t)(b * SEQ + qr + l31)) * D_MODEL + h * 64 + hi * 4;
    #pragma unroll
    for (int g = 0; g < 4; g++) {
      bf16x4 o0, o1;
      #pragma unroll
      for (int e = 0; e < 4; e++) {
        o0[e] = (bf16)(acc0[4*g + e] * fa + src[4*g + e] * fb);
        o1[e] = (bf16)(acc1[4*g + e] * fa + src[16 + 4*g + e] * fb);
      }
      *(bf16x4*)&orow[8 * g]      = o0;   // d = 8g + 4hi + e
      *(bf16x4*)&orow[32 + 8 * g] = o1;   // d = 32 + 8g + 4hi + e
    }
  }
}

// ---------------- launch ----------------

extern "C" void kernel_launch(void* const* d_in, const int* in_sizes, int n_in,
                              void* d_out, int out_size, void* d_ws, size_t ws_size,
                              hipStream_t stream) {
  const float* x      = (const float*)d_in[0];
  const float* w_qkv  = (const float*)d_in[1];
  const float* w_proj = (const float*)d_in[2];
  float* outf = (float*)d_out;

  bf16* xb    = (bf16*)d_ws;                                 // 4096*1024
  bf16* wqkvT = xb    + (size_t)MROWS * D_MODEL;             // 3072*1024
  bf16* wpT   = wqkvT + (size_t)3 * D_MODEL * D_MODEL;       // 1024*1024
  bf16* qb    = wpT   + (size_t)D_MODEL * D_MODEL;           // 32*2048*64
  bf16* kb    = qb    + (size_t)BHTOT * SEQ * DHEAD;
  bf16* vtb   = kb    + (size_t)BHTOT * SEQ * DHEAD;         // [BH][64][SEQ]
  bf16* ob    = xb;   // alias: xb dead after GEMM1

  dim3 tb(32, 8);

  cast_f32_bf16<<<(MROWS * D_MODEL / 4 + 255) / 256, 256, 0, stream>>>(
      x, xb, MROWS * D_MODEL / 4);
  tcast<<<dim3(3 * D_MODEL / 32, D_MODEL / 32), tb, 0, stream>>>(
      w_qkv, wqkvT, D_MODEL, 3 * D_MODEL);
  tcast<<<dim3(D_MODEL / 32, D_MODEL / 32), tb, 0, stream>>>(
      w_proj, wpT, D_MODEL, D_MODEL);

  gemm_bt<0><<<dim3(3 * D_MODEL / 128, MROWS / 128), 256, 0, stream>>>(
      xb, wqkvT, D_MODEL, 3 * D_MODEL, qb, kb, vtb, nullptr, nullptr);

  attn_kernel<<<dim3(SEQ / 128, BHTOT), 512, 0, stream>>>(qb, kb, vtb, ob);

  gemm_bt<1><<<dim3(D_MODEL / 128, MROWS / 128), 256, 0, stream>>>(
      ob, wpT, D_MODEL, D_MODEL, nullptr, nullptr, nullptr, x, outf);
}